// Round 10
// baseline (161.485 us; speedup 1.0000x reference)
//
#include <hip/hip_runtime.h>
#include <hip/hip_bf16.h>
#include <stdint.h>

// Problem constants (B=8, S=512, D=1024)
constexpr int N_TOK  = 4096;   // B*S
constexpr int D_DIM  = 1024;
constexpr int MASK_ID_V = 8192;

// Fast path: 256x256 tiles, 8 waves (2Mx4N, per-wave 128x64), fp8 MX
// 32x32x64 scaled MFMA, BK=64 K-tiles, ring-4 LDS, prefetch distance 3,
// two double-barrier phases per K-tile (m201-style interleave)
constexpr int BM2  = 256;
constexpr int KIT2 = D_DIM / 64;     // 16 K-tiles
constexpr int NSL2 = N_TOK / BM2;    // 16 col slices
constexpr int NPART = NSL2 * 4;      // 64 partials/row (4 wc-waves per slice)

constexpr float SCALE   = 64.0f;     // pre-scale into e4m3 normal range
constexpr float INVSC2  = 1.0f / (SCALE * SCALE);

// Fallback tiling (used only if ws too small)
constexpr int BM = 128, BN = 128, BK = 64;
constexpr int KST = D_DIM / BK;
constexpr int NSLICE_FB = 8;
constexpr int SLICE_W   = N_TOK / NSLICE_FB;
constexpr int CTS       = SLICE_W / BN;
constexpr int LDW       = BK + 8;
constexpr int NPART_FB  = NSLICE_FB * 2;

constexpr int FIN_BLOCKS = 256;

typedef __attribute__((ext_vector_type(4)))  float f32x4;
typedef __attribute__((ext_vector_type(16))) float f32x16;
typedef __attribute__((ext_vector_type(8)))  short bf16x8;
typedef __attribute__((ext_vector_type(8)))  int   i32x8;

__device__ __forceinline__ uint32_t pk2bf(float lo, float hi) {
    union { float f; uint32_t u; } a, b;
    a.f = lo; b.f = hi;
    uint32_t ua = (a.u + 0x7fffu + ((a.u >> 16) & 1u)) >> 16;
    uint32_t ub = (b.u + 0x7fffu + ((b.u >> 16) & 1u)) >> 16;
    return ua | (ub << 16);
}

__device__ __forceinline__ void async16(void* lds, const void* g) {
    __builtin_amdgcn_global_load_lds(
        (const __attribute__((address_space(1))) uint32_t*)g,
        (__attribute__((address_space(3))) uint32_t*)lds,
        16, 0, 0);
}

#define BAR   do { __builtin_amdgcn_s_barrier(); __builtin_amdgcn_sched_barrier(0); } while (0)
#define LGKM0 do { asm volatile("s_waitcnt lgkmcnt(0)" ::: "memory"); __builtin_amdgcn_sched_barrier(0); } while (0)
#define VMC(N) do { asm volatile("s_waitcnt vmcnt(" #N ")" ::: "memory"); __builtin_amdgcn_sched_barrier(0); } while (0)

// ---------------------------------------------------------------------------
// Pass 1: fp32 -> fp8 e4m3 (OCP) pre-convert with fixed x64 pre-scale
// ---------------------------------------------------------------------------
__device__ __forceinline__ uint pk4fp8(float4 v) {
    int w = __builtin_amdgcn_cvt_pk_fp8_f32(v.x * SCALE, v.y * SCALE, 0, false);
    w = __builtin_amdgcn_cvt_pk_fp8_f32(v.z * SCALE, v.w * SCALE, w, true);
    return (uint)w;
}

__global__ __launch_bounds__(256) void conv_fp8(
    const float* __restrict__ x, const float* __restrict__ e,
    unsigned char* __restrict__ xb8, unsigned char* __restrict__ eb8)
{
    constexpr int NC = N_TOK * D_DIM / 16;
    const int t0 = blockIdx.x * blockDim.x + threadIdx.x;
    const int stride = gridDim.x * blockDim.x;
    for (int c = t0; c < NC; c += stride) {
        const float4* px = (const float4*)x + (size_t)c * 4;
        uint4 o;
        o.x = pk4fp8(px[0]); o.y = pk4fp8(px[1]);
        o.z = pk4fp8(px[2]); o.w = pk4fp8(px[3]);
        ((uint4*)xb8)[c] = o;

        const float4* pe = (const float4*)e + (size_t)c * 4;
        uint4 q;
        q.x = pk4fp8(pe[0]); q.y = pk4fp8(pe[1]);
        q.z = pk4fp8(pe[2]); q.w = pk4fp8(pe[3]);
        ((uint4*)eb8)[c] = q;
    }
}

// ---------------------------------------------------------------------------
// Pass 2: fp8 MX GEMM — 8 waves, phased interleave, deep ring, counted vmcnt
// ---------------------------------------------------------------------------
__device__ __forceinline__ i32x8 ld_frag(const unsigned char* base, int o0, int o1) {
    uint4 u = *(const uint4*)(base + o0);
    uint4 v = *(const uint4*)(base + o1);
    i32x8 r = { (int)u.x, (int)u.y, (int)u.z, (int)u.w,
                (int)v.x, (int)v.y, (int)v.z, (int)v.w };
    return r;
}

#define MFMA8(A_, B_, C_) __builtin_amdgcn_mfma_scale_f32_32x32x64_f8f6f4( \
    A_, B_, C_, 0, 0, 0, 127, 0, 127)

__global__ __launch_bounds__(512, 2) void nce_gemm_fp8(
    const unsigned char* __restrict__ xb8,   // [N_TOK][1024] fp8 keys (x*64)
    const unsigned char* __restrict__ eb8,   // [N_TOK][1024] fp8 queries
    float* __restrict__ numer,
    float* __restrict__ pm,
    float* __restrict__ ps)
{
    __shared__ unsigned char As[4][16384];   // ring-4 K-tiles: 256 rows x 64 B
    __shared__ unsigned char Bs[4][16384];   // total 128 KB

    // Bijective XCD-chunked swizzle: each XCD -> two 4x4 tile-chunks
    const int bid   = blockIdx.x;
    const int sw_   = (bid & 7) * 32 + (bid >> 3);
    const int chunk = sw_ >> 4, win = sw_ & 15;
    const int rb    = (chunk & 3) * 4 + (win & 3);
    const int cs    = (chunk >> 2) * 4 + (win >> 2);
    const int row0  = rb * BM2;
    const int col0  = cs * BM2;

    const int tid  = threadIdx.x;
    const int lane = tid & 63;
    const int wid  = tid >> 6;         // 0..7
    const int wr   = wid >> 2;         // 0..1  (M-warps, 128 rows each)
    const int wc   = wid & 3;          // 0..3  (N-warps, 64 cols each)
    const int l31  = lane & 31;
    const int lg   = lane >> 5;

    // Staging: tile = 1024 chunks of 16B; wave does 2 wave-loads (s=0,1).
    // chunk ch = (wid*2+s)*64 + lane; row = ch>>2; dest slot = ch&3 (linear);
    // source slot = (ch&3) ^ ((row>>1)&3)   [involution swizzle, both sides]
    const int ch0 = (wid * 2 + 0) * 64 + lane;
    const int ch1 = (wid * 2 + 1) * 64 + lane;
    const int r0_ = ch0 >> 2, s0_ = (ch0 & 3) ^ ((r0_ >> 1) & 3);
    const int r1_ = ch1 >> 2, s1_ = (ch1 & 3) ^ ((r1_ >> 1) & 3);
    const unsigned char* gA0 = eb8 + (size_t)(row0 + r0_) * D_DIM + s0_ * 16;
    const unsigned char* gA1 = eb8 + (size_t)(row0 + r1_) * D_DIM + s1_ * 16;
    const unsigned char* gB0 = xb8 + (size_t)(col0 + r0_) * D_DIM + s0_ * 16;
    const unsigned char* gB1 = xb8 + (size_t)(col0 + r1_) * D_DIM + s1_ * 16;
    const int d0 = (wid * 2 + 0) * 1024;
    const int d1 = (wid * 2 + 1) * 1024;

    // Frag read offsets. A: rows wr*128 + mf*32 + l31 (mf via +2048B);
    // B: rows wc*64 + nf*32 + l31 (nf via +2048B). swz invariant in mf/nf.
    const int rA  = wr * 128 + l31;
    const int swA = (rA >> 1) & 3;
    const int oA0 = rA * 64 + (((lg * 2 + 0) ^ swA) << 4);
    const int oA1 = rA * 64 + (((lg * 2 + 1) ^ swA) << 4);
    const int rB  = wc * 64 + l31;
    const int swB = (rB >> 1) & 3;
    const int oB0 = rB * 64 + (((lg * 2 + 0) ^ swB) << 4);
    const int oB1 = rB * 64 + (((lg * 2 + 1) ^ swB) << 4);

    f32x16 acc[4][2];
#pragma unroll
    for (int a = 0; a < 4; ++a)
#pragma unroll
        for (int b = 0; b < 2; ++b)
#pragma unroll
            for (int i = 0; i < 16; ++i) acc[a][b][i] = 0.f;

#define STG_A(T) do { async16(As[(T) & 3] + d0, gA0 + (T) * 64); \
                      async16(As[(T) & 3] + d1, gA1 + (T) * 64); } while (0)
#define STG_B(T) do { async16(Bs[(T) & 3] + d0, gB0 + (T) * 64); \
                      async16(Bs[(T) & 3] + d1, gB1 + (T) * 64); } while (0)

    // Prologue: stage tiles 0,1,2 (12 loads); retire tile 0 (vmcnt 8); barrier
    STG_A(0); STG_B(0); STG_A(1); STG_B(1); STG_A(2); STG_B(2);
    VMC(8); BAR;

#pragma unroll
    for (int t = 0; t < KIT2; ++t) {
        const unsigned char* Ab = As[t & 3];
        const unsigned char* Bb = Bs[t & 3];

        // ---- phase A: reads(B0,B1,A0,A1) + stage A(t+3) + 4 MFMA ----
        i32x8 b0 = ld_frag(Bb,        oB0, oB1);
        i32x8 b1 = ld_frag(Bb + 2048, oB0, oB1);
        i32x8 a0 = ld_frag(Ab,        oA0, oA1);
        i32x8 a1 = ld_frag(Ab + 2048, oA0, oA1);
        if (t <= KIT2 - 4) STG_A(t + 3);   // slot (t+3)&3 == (t-1)&3: readers
                                           // retired before prev closing BAR
        BAR; LGKM0;
        __builtin_amdgcn_s_setprio(1);
        acc[0][0] = MFMA8(a0, b0, acc[0][0]);
        acc[0][1] = MFMA8(a0, b1, acc[0][1]);
        acc[1][0] = MFMA8(a1, b0, acc[1][0]);
        acc[1][1] = MFMA8(a1, b1, acc[1][1]);
        __builtin_amdgcn_s_setprio(0);
        BAR;

        // ---- phase B: reads(A2,A3) + stage B(t+3) + counted vmcnt + 4 MFMA --
        i32x8 a2 = ld_frag(Ab + 4096, oA0, oA1);
        i32x8 a3 = ld_frag(Ab + 6144, oA0, oA1);
        if (t <= KIT2 - 4) STG_B(t + 3);
        // Need tile t+1 resident after this phase's barrier.
        // Outstanding here: tiles t+1,t+2,t+3 (4 loads each) while staging on.
        if      (t <= KIT2 - 4) { VMC(8); }   // leave t+2,t+3 in flight
        else if (t == KIT2 - 3) { VMC(4); }   // leave t+2 (=15) in flight
        else if (t == KIT2 - 2) { VMC(0); }   // last tile must land
        BAR; LGKM0;
        __builtin_amdgcn_s_setprio(1);
        acc[2][0] = MFMA8(a2, b0, acc[2][0]);
        acc[2][1] = MFMA8(a2, b1, acc[2][1]);
        acc[3][0] = MFMA8(a3, b0, acc[3][0]);
        acc[3][1] = MFMA8(a3, b1, acc[3][1]);
        __builtin_amdgcn_s_setprio(0);
        BAR;
    }

    // Epilogue. 32x32 C/D: col = lane&31, row = (reg&3)+8*(reg>>2)+4*lg.
    const int c0g = col0 + wc * 64 + l31;   // nf=0 col
    const int c1g = c0g + 32;               // nf=1 col

#pragma unroll
    for (int mf = 0; mf < 4; ++mf)
#pragma unroll
        for (int reg = 0; reg < 16; ++reg) {
            const int rif   = (reg & 3) + 8 * (reg >> 2) + 4 * lg;
            const int row_g = row0 + wr * 128 + mf * 32 + rif;
            const float v0 = acc[mf][0][reg] * INVSC2;
            const float v1 = acc[mf][1][reg] * INVSC2;
            if (row_g == c0g) numer[row_g] = v0;
            if (row_g == c1g) numer[row_g] = v1;
            float m = fmaxf(v0, v1);
#pragma unroll
            for (int off = 1; off <= 16; off <<= 1)
                m = fmaxf(m, __shfl_xor(m, off, 64));
            float s = __expf(v0 - m) + __expf(v1 - m);
#pragma unroll
            for (int off = 1; off <= 16; off <<= 1)
                s += __shfl_xor(s, off, 64);
            if (l31 == 0) {
                pm[row_g * NPART + cs * 4 + wc] = m;
                ps[row_g * NPART + cs * 4 + wc] = s;
            }
        }
}

// ---------------------------------------------------------------------------
// Pass 3a: one WAVE per row — coalesced partial combine + masked row loss
// ---------------------------------------------------------------------------
__global__ __launch_bounds__(256) void nce_finish_a(
    const int* __restrict__ tgt,
    const float* __restrict__ numer,
    const float* __restrict__ pm,
    const float* __restrict__ ps,
    float* __restrict__ bl_loss,
    float* __restrict__ bl_cnt,
    int npart)
{
    const int tid  = threadIdx.x;
    const int lane = tid & 63;
    const int wv   = tid >> 6;
    const int waves_total = gridDim.x * 4;

    float loss = 0.f, cnt = 0.f;

    for (int row = blockIdx.x * 4 + wv; row < N_TOK; row += waves_total) {
        if (tgt[row] != MASK_ID_V) continue;
        float pmv = -3.0e38f, psv = 0.f;
        if (lane < npart) {
            pmv = pm[row * npart + lane];
            psv = ps[row * npart + lane];
        }
        float m = pmv;
#pragma unroll
        for (int off = 32; off; off >>= 1) m = fmaxf(m, __shfl_xor(m, off, 64));
        float sv = psv * __expf(pmv - m);
#pragma unroll
        for (int off = 32; off; off >>= 1) sv += __shfl_xor(sv, off, 64);
        if (lane == 0) {
            loss += numer[row] - (m + __logf(sv));
            cnt  += 1.f;
        }
    }

    __shared__ float sl[4], sc[4];
    if (lane == 0) { sl[wv] = loss; sc[wv] = cnt; }
    __syncthreads();
    if (tid == 0) {
        bl_loss[blockIdx.x] = sl[0] + sl[1] + sl[2] + sl[3];
        bl_cnt[blockIdx.x]  = sc[0] + sc[1] + sc[2] + sc[3];
    }
}

__global__ __launch_bounds__(256) void nce_finish_b(
    const float* __restrict__ bl_loss,
    const float* __restrict__ bl_cnt,
    float* __restrict__ out, int nblk)
{
    const int tid = threadIdx.x;
    float l = 0.f, c = 0.f;
    for (int i = tid; i < nblk; i += 256) { l += bl_loss[i]; c += bl_cnt[i]; }
    __shared__ float sl[256], sc[256];
    sl[tid] = l; sc[tid] = c;
    __syncthreads();
    for (int off = 128; off; off >>= 1) {
        if (tid < off) { sl[tid] += sl[tid + off]; sc[tid] += sc[tid + off]; }
        __syncthreads();
    }
    if (tid == 0) out[0] = -(sl[0] / sc[0]);
}

// ---------------------------------------------------------------------------
// Fallback (bf16 on-the-fly convert) — only if ws too small
// ---------------------------------------------------------------------------
__global__ __launch_bounds__(256, 2) void nce_gemm_fb(
    const float* __restrict__ x, const float* __restrict__ emb,
    float* __restrict__ numer, float* __restrict__ pm, float* __restrict__ ps)
{
    __shared__ ushort At[BM][LDW];
    __shared__ ushort Bt[BN][LDW];

    const int rb = blockIdx.x, cs = blockIdx.y;
    const int row0 = rb * BM, col0 = cs * SLICE_W;
    const int tid = threadIdx.x, lane = tid & 63, wid = tid >> 6;
    const int wr = wid >> 1, wc = wid & 1, l15 = lane & 15, lhi = lane >> 4;

    float m_run[16], s_run[16];
#pragma unroll
    for (int i = 0; i < 16; ++i) { m_run[i] = -3.0e38f; s_run[i] = 0.0f; }

    for (int ct = 0; ct < CTS; ++ct) {
        const int colt0 = col0 + ct * BN;
        f32x4 acc[4][4];
#pragma unroll
        for (int a = 0; a < 4; ++a)
#pragma unroll
            for (int b = 0; b < 4; ++b) acc[a][b] = f32x4{0.f,0.f,0.f,0.f};

#pragma unroll 1
        for (int kt = 0; kt < KST; ++kt) {
            __syncthreads();
#pragma unroll
            for (int i = 0; i < 4; ++i) {
                const int chunk = tid + i * 256;
                const int r = chunk >> 3, c8 = (chunk & 7) << 3;
                const float* ga = emb + (size_t)(row0 + r) * D_DIM + kt * BK + c8;
                float4 a0 = *(const float4*)(ga); float4 a1 = *(const float4*)(ga + 4);
                uint4 pa;
                pa.x = pk2bf(a0.x, a0.y); pa.y = pk2bf(a0.z, a0.w);
                pa.z = pk2bf(a1.x, a1.y); pa.w = pk2bf(a1.z, a1.w);
                *(uint4*)&At[r][c8] = pa;
                const float* gb = x + (size_t)(colt0 + r) * D_DIM + kt * BK + c8;
                float4 b0 = *(const float4*)(gb); float4 b1 = *(const float4*)(gb + 4);
                uint4 pb;
                pb.x = pk2bf(b0.x, b0.y); pb.y = pk2bf(b0.z, b0.w);
                pb.z = pk2bf(b1.x, b1.y); pb.w = pk2bf(b1.z, b1.w);
                *(uint4*)&Bt[r][c8] = pb;
            }
            __syncthreads();
#pragma unroll
            for (int kp = 0; kp < 2; ++kp) {
                const int ko = kp * 32 + lhi * 8;
                bf16x8 af[4], bfr[4];
#pragma unroll
                for (int mi = 0; mi < 4; ++mi)
                    af[mi] = *(const bf16x8*)&At[wr*64 + mi*16 + l15][ko];
#pragma unroll
                for (int ni = 0; ni < 4; ++ni)
                    bfr[ni] = *(const bf16x8*)&Bt[wc*64 + ni*16 + l15][ko];
#pragma unroll
                for (int mi = 0; mi < 4; ++mi)
#pragma unroll
                    for (int ni = 0; ni < 4; ++ni)
                        acc[mi][ni] = __builtin_amdgcn_mfma_f32_16x16x32_bf16(
                            af[mi], bfr[ni], acc[mi][ni], 0, 0, 0);
            }
        }

#pragma unroll
        for (int mi = 0; mi < 4; ++mi)
#pragma unroll
            for (int r = 0; r < 4; ++r) {
                const int row_g = row0 + wr*64 + mi*16 + lhi*4 + r;
#pragma unroll
                for (int ni = 0; ni < 4; ++ni) {
                    const int col_g = colt0 + wc*64 + ni*16 + l15;
                    if (row_g == col_g) numer[row_g] = acc[mi][ni][r];
                }
                const int idx = mi * 4 + r;
                const float v0 = acc[mi][0][r], v1 = acc[mi][1][r];
                const float v2 = acc[mi][2][r], v3 = acc[mi][3][r];
                const float mx = fmaxf(fmaxf(v0, v1), fmaxf(v2, v3));
                const float mn = fmaxf(m_run[idx], mx);
                const float scale = __expf(m_run[idx] - mn);
                s_run[idx] = s_run[idx] * scale
                           + __expf(v0 - mn) + __expf(v1 - mn)
                           + __expf(v2 - mn) + __expf(v3 - mn);
                m_run[idx] = mn;
            }
    }

#pragma unroll
    for (int idx = 0; idx < 16; ++idx) {
        float m = m_run[idx], s = s_run[idx];
#pragma unroll
        for (int off = 1; off < 16; off <<= 1) {
            const float mo = __shfl_xor(m, off, 64);
            const float so = __shfl_xor(s, off, 64);
            const float mn = fmaxf(m, mo);
            s = s * __expf(m - mn) + so * __expf(mo - mn);
            m = mn;
        }
        m_run[idx] = m; s_run[idx] = s;
    }

    if (l15 == 0) {
        const int slot = cs * 2 + wc;
#pragma unroll
        for (int mi = 0; mi < 4; ++mi)
#pragma unroll
            for (int r = 0; r < 4; ++r) {
                const int row_g = row0 + wr*64 + mi*16 + lhi*4 + r;
                pm[row_g * NPART_FB + slot] = m_run[mi*4 + r];
                ps[row_g * NPART_FB + slot] = s_run[mi*4 + r];
            }
    }
}

extern "C" void kernel_launch(void* const* d_in, const int* in_sizes, int n_in,
                              void* d_out, int out_size, void* d_ws, size_t ws_size,
                              hipStream_t stream) {
    (void)in_sizes; (void)n_in; (void)out_size;
    const float* x   = (const float*)d_in[0];
    const float* emb = (const float*)d_in[1];
    const int*   tgt = (const int*)d_in[2];
    float* out = (float*)d_out;

    const size_t elems = (size_t)N_TOK * D_DIM;
    const size_t need  = elems * 2
                       + (size_t)N_TOK * 4
                       + (size_t)N_TOK * NPART * 4 * 2
                       + FIN_BLOCKS * 8;

    if (ws_size >= need) {
        unsigned char* xb8 = (unsigned char*)d_ws;
        unsigned char* eb8 = xb8 + elems;
        float* numer = (float*)(eb8 + elems);
        float* pm    = numer + N_TOK;
        float* ps    = pm + (size_t)N_TOK * NPART;
        float* bl    = ps + (size_t)N_TOK * NPART;
        float* bc    = bl + FIN_BLOCKS;

        conv_fp8<<<1024, 256, 0, stream>>>(x, emb, xb8, eb8);
        nce_gemm_fp8<<<NSL2 * NSL2, 512, 0, stream>>>(xb8, eb8, numer, pm, ps);
        nce_finish_a<<<FIN_BLOCKS, 256, 0, stream>>>(tgt, numer, pm, ps, bl, bc, NPART);
        nce_finish_b<<<1, 256, 0, stream>>>(bl, bc, out, FIN_BLOCKS);
    } else {
        float* numer = (float*)d_ws;
        float* pm    = numer + N_TOK;
        float* ps    = pm + (size_t)N_TOK * NPART_FB;
        float* bl    = ps + (size_t)N_TOK * NPART_FB;
        float* bc    = bl + FIN_BLOCKS;
        nce_gemm_fb<<<dim3(N_TOK / BM, NSLICE_FB), 256, 0, stream>>>(x, emb, numer, pm, ps);
        nce_finish_a<<<FIN_BLOCKS, 256, 0, stream>>>(tgt, numer, pm, ps, bl, bc, NPART_FB);
        nce_finish_b<<<1, 256, 0, stream>>>(bl, bc, out, FIN_BLOCKS);
    }
}

// Round 11
// 66.292 us; speedup vs baseline: 2.4360x; 2.4360x over previous
//
#include <hip/hip_runtime.h>
#include <hip/hip_bf16.h>
#include <stdint.h>

// Problem constants (B=8, S=512, D=1024)
constexpr int N_TOK  = 4096;   // B*S
constexpr int D_DIM  = 1024;
constexpr int MASK_ID_V = 8192;

// Fast path: m97/m148 structure — 128x128 tiles, 4 waves (2x2 of 64x64),
// fp8 MX 32x32x64 scaled MFMA, BK=128 per stage, single-buffer LDS (32 KB),
// 2 barriers per K-step, multi-block-per-CU TLP
constexpr int BMX  = 128;
constexpr int KIT3 = D_DIM / 128;    // 8 K-steps
constexpr int NSL3 = N_TOK / BMX;    // 32 col slices
constexpr int NPART3 = NSL3 * 2;     // 64 partials/row (2 wc-waves per slice)

constexpr float SCALE   = 64.0f;     // pre-scale into e4m3 normal range
constexpr float INVSC2  = 1.0f / (SCALE * SCALE);

// Fallback tiling (used only if ws too small)
constexpr int BM = 128, BN = 128, BK = 64;
constexpr int KST = D_DIM / BK;
constexpr int NSLICE_FB = 8;
constexpr int SLICE_W   = N_TOK / NSLICE_FB;
constexpr int CTS       = SLICE_W / BN;
constexpr int LDW       = BK + 8;
constexpr int NPART_FB  = NSLICE_FB * 2;

constexpr int FIN_BLOCKS = 256;

typedef __attribute__((ext_vector_type(4)))  float f32x4;
typedef __attribute__((ext_vector_type(16))) float f32x16;
typedef __attribute__((ext_vector_type(8)))  short bf16x8;
typedef __attribute__((ext_vector_type(8)))  int   i32x8;

__device__ __forceinline__ uint32_t pk2bf(float lo, float hi) {
    union { float f; uint32_t u; } a, b;
    a.f = lo; b.f = hi;
    uint32_t ua = (a.u + 0x7fffu + ((a.u >> 16) & 1u)) >> 16;
    uint32_t ub = (b.u + 0x7fffu + ((b.u >> 16) & 1u)) >> 16;
    return ua | (ub << 16);
}

__device__ __forceinline__ void async16(void* lds, const void* g) {
    __builtin_amdgcn_global_load_lds(
        (const __attribute__((address_space(1))) uint32_t*)g,
        (__attribute__((address_space(3))) uint32_t*)lds,
        16, 0, 0);
}

#define BAR do { __builtin_amdgcn_s_barrier(); __builtin_amdgcn_sched_barrier(0); } while (0)

// ---------------------------------------------------------------------------
// Pass 1: fp32 -> fp8 e4m3 (OCP) pre-convert with fixed x64 pre-scale
// ---------------------------------------------------------------------------
__device__ __forceinline__ uint pk4fp8(float4 v) {
    int w = __builtin_amdgcn_cvt_pk_fp8_f32(v.x * SCALE, v.y * SCALE, 0, false);
    w = __builtin_amdgcn_cvt_pk_fp8_f32(v.z * SCALE, v.w * SCALE, w, true);
    return (uint)w;
}

__global__ __launch_bounds__(256) void conv_fp8(
    const float* __restrict__ x, const float* __restrict__ e,
    unsigned char* __restrict__ xb8, unsigned char* __restrict__ eb8)
{
    constexpr int NC = N_TOK * D_DIM / 16;
    const int t0 = blockIdx.x * blockDim.x + threadIdx.x;
    const int stride = gridDim.x * blockDim.x;
    for (int c = t0; c < NC; c += stride) {
        const float4* px = (const float4*)x + (size_t)c * 4;
        uint4 o;
        o.x = pk4fp8(px[0]); o.y = pk4fp8(px[1]);
        o.z = pk4fp8(px[2]); o.w = pk4fp8(px[3]);
        ((uint4*)xb8)[c] = o;

        const float4* pe = (const float4*)e + (size_t)c * 4;
        uint4 q;
        q.x = pk4fp8(pe[0]); q.y = pk4fp8(pe[1]);
        q.z = pk4fp8(pe[2]); q.w = pk4fp8(pe[3]);
        ((uint4*)eb8)[c] = q;
    }
}

// ---------------------------------------------------------------------------
// Pass 2: fp8 MX GEMM — m97 structure, 128^2 tile, 4 waves, 2 barriers/K-step
// ---------------------------------------------------------------------------
__device__ __forceinline__ i32x8 ld_frag(const unsigned char* base, int o0, int o1) {
    uint4 u = *(const uint4*)(base + o0);
    uint4 v = *(const uint4*)(base + o1);
    i32x8 r = { (int)u.x, (int)u.y, (int)u.z, (int)u.w,
                (int)v.x, (int)v.y, (int)v.z, (int)v.w };
    return r;
}

#define MFMA8(A_, B_, C_) __builtin_amdgcn_mfma_scale_f32_32x32x64_f8f6f4( \
    A_, B_, C_, 0, 0, 0, 127, 0, 127)

__global__ __launch_bounds__(256, 3) void nce_gemm_mx(
    const unsigned char* __restrict__ xb8,   // [N_TOK][1024] fp8 keys (x*64)
    const unsigned char* __restrict__ eb8,   // [N_TOK][1024] fp8 queries
    float* __restrict__ numer,
    float* __restrict__ pm,
    float* __restrict__ ps)
{
    __shared__ unsigned char As[16384];   // [128 rows][128 B], single buffer
    __shared__ unsigned char Bs[16384];   // total 32 KB -> 3-5 blocks/CU

    // Bijective XCD swizzle (1024 blocks, 1024%8==0): each XCD gets 4 col
    // slices x all row blocks -> B-panel 512 KB + A-panel 4 MB fit its L2.
    const int bid  = blockIdx.x;
    const int sw_  = (bid & 7) * 128 + (bid >> 3);
    const int rb   = sw_ & 31;
    const int cs   = sw_ >> 5;
    const int row0 = rb * BMX;
    const int col0 = cs * BMX;

    const int tid  = threadIdx.x;
    const int lane = tid & 63;
    const int wid  = tid >> 6;         // 0..3
    const int wr   = wid >> 1;         // 0..1 (M-waves, 64 rows)
    const int wc   = wid & 1;          // 0..1 (N-waves, 64 cols)
    const int l31  = lane & 31;
    const int lg   = lane >> 5;        // 0..1

    // Staging: 1024 chunks of 16B per matrix; wave does 4 wave-instrs each.
    // chunk q = wid*256 + j*64 + lane; row = q>>3; dest slot = q&7 (linear);
    // source slot = (q&7) ^ (row&7)   [involution swizzle, both sides]
    const unsigned char* gA[4];
    const unsigned char* gB[4];
    int dst[4];
#pragma unroll
    for (int j = 0; j < 4; ++j) {
        const int q   = wid * 256 + j * 64 + lane;
        const int row = q >> 3;
        const int sl  = (q & 7) ^ (row & 7);
        gA[j]  = eb8 + (size_t)(row0 + row) * D_DIM + sl * 16;
        gB[j]  = xb8 + (size_t)(col0 + row) * D_DIM + sl * 16;
        dst[j] = q * 16;
    }

    // Frag read offsets: row r (128B rows), K=64 sub-tile ks: logical slots
    // 4ks + lg*2 + {0,1}; phys = logical ^ (r&7). mf/nf add 32 rows (+4096B),
    // leaving r&7 unchanged.
    const int rA  = wr * 64 + l31;
    const int swA = rA & 7;
    const int rB  = wc * 64 + l31;
    const int swB = rB & 7;
    int oA[2][2], oB[2][2];
#pragma unroll
    for (int ks = 0; ks < 2; ++ks)
#pragma unroll
        for (int j = 0; j < 2; ++j) {
            oA[ks][j] = rA * 128 + (((ks * 4 + lg * 2 + j) ^ swA) << 4);
            oB[ks][j] = rB * 128 + (((ks * 4 + lg * 2 + j) ^ swB) << 4);
        }

    f32x16 acc00, acc01, acc10, acc11;
#pragma unroll
    for (int i = 0; i < 16; ++i) { acc00[i] = 0.f; acc01[i] = 0.f; acc10[i] = 0.f; acc11[i] = 0.f; }

#pragma unroll 1
    for (int kt = 0; kt < KIT3; ++kt) {
        BAR;   // all waves finished reading the buffer (previous iteration)
#pragma unroll
        for (int j = 0; j < 4; ++j) async16(As + dst[j], gA[j] + kt * 128);
#pragma unroll
        for (int j = 0; j < 4; ++j) async16(Bs + dst[j], gB[j] + kt * 128);
        asm volatile("s_waitcnt vmcnt(0)" ::: "memory");
        BAR;   // whole tile resident

#pragma unroll
        for (int ks = 0; ks < 2; ++ks) {
            i32x8 a0 = ld_frag(As,        oA[ks][0], oA[ks][1]);
            i32x8 a1 = ld_frag(As + 4096, oA[ks][0], oA[ks][1]);
            i32x8 b0 = ld_frag(Bs,        oB[ks][0], oB[ks][1]);
            i32x8 b1 = ld_frag(Bs + 4096, oB[ks][0], oB[ks][1]);
            __builtin_amdgcn_s_setprio(1);
            acc00 = MFMA8(a0, b0, acc00);
            acc01 = MFMA8(a0, b1, acc01);
            acc10 = MFMA8(a1, b0, acc10);
            acc11 = MFMA8(a1, b1, acc11);
            __builtin_amdgcn_s_setprio(0);
        }
    }

    // Epilogue. 32x32 C/D: col = lane&31, row = (reg&3)+8*(reg>>2)+4*lg
    // (hardware-verified by r8's absmax==0 pass).
    const int c0g = col0 + wc * 64 + l31;   // nf=0 col
    const int c1g = c0g + 32;               // nf=1 col

#pragma unroll
    for (int mf = 0; mf < 2; ++mf)
#pragma unroll
        for (int reg = 0; reg < 16; ++reg) {
            const int rif   = (reg & 3) + 8 * (reg >> 2) + 4 * lg;
            const int row_g = row0 + wr * 64 + mf * 32 + rif;
            const float v0 = (mf ? acc10[reg] : acc00[reg]) * INVSC2;
            const float v1 = (mf ? acc11[reg] : acc01[reg]) * INVSC2;
            if (row_g == c0g) numer[row_g] = v0;
            if (row_g == c1g) numer[row_g] = v1;
            float m = fmaxf(v0, v1);
#pragma unroll
            for (int off = 1; off <= 16; off <<= 1)
                m = fmaxf(m, __shfl_xor(m, off, 64));
            float s = __expf(v0 - m) + __expf(v1 - m);
#pragma unroll
            for (int off = 1; off <= 16; off <<= 1)
                s += __shfl_xor(s, off, 64);
            if (l31 == 0) {
                pm[row_g * NPART3 + cs * 2 + wc] = m;
                ps[row_g * NPART3 + cs * 2 + wc] = s;
            }
        }
}

// ---------------------------------------------------------------------------
// Pass 3a: one WAVE per row — coalesced partial combine + masked row loss
// ---------------------------------------------------------------------------
__global__ __launch_bounds__(256) void nce_finish_a(
    const int* __restrict__ tgt,
    const float* __restrict__ numer,
    const float* __restrict__ pm,
    const float* __restrict__ ps,
    float* __restrict__ bl_loss,
    float* __restrict__ bl_cnt,
    int npart)
{
    const int tid  = threadIdx.x;
    const int lane = tid & 63;
    const int wv   = tid >> 6;
    const int waves_total = gridDim.x * 4;

    float loss = 0.f, cnt = 0.f;

    for (int row = blockIdx.x * 4 + wv; row < N_TOK; row += waves_total) {
        if (tgt[row] != MASK_ID_V) continue;
        float pmv = -3.0e38f, psv = 0.f;
        if (lane < npart) {
            pmv = pm[row * npart + lane];
            psv = ps[row * npart + lane];
        }
        float m = pmv;
#pragma unroll
        for (int off = 32; off; off >>= 1) m = fmaxf(m, __shfl_xor(m, off, 64));
        float sv = psv * __expf(pmv - m);
#pragma unroll
        for (int off = 32; off; off >>= 1) sv += __shfl_xor(sv, off, 64);
        if (lane == 0) {
            loss += numer[row] - (m + __logf(sv));
            cnt  += 1.f;
        }
    }

    __shared__ float sl[4], sc[4];
    if (lane == 0) { sl[wv] = loss; sc[wv] = cnt; }
    __syncthreads();
    if (tid == 0) {
        bl_loss[blockIdx.x] = sl[0] + sl[1] + sl[2] + sl[3];
        bl_cnt[blockIdx.x]  = sc[0] + sc[1] + sc[2] + sc[3];
    }
}

__global__ __launch_bounds__(256) void nce_finish_b(
    const float* __restrict__ bl_loss,
    const float* __restrict__ bl_cnt,
    float* __restrict__ out, int nblk)
{
    const int tid = threadIdx.x;
    float l = 0.f, c = 0.f;
    for (int i = tid; i < nblk; i += 256) { l += bl_loss[i]; c += bl_cnt[i]; }
    __shared__ float sl[256], sc[256];
    sl[tid] = l; sc[tid] = c;
    __syncthreads();
    for (int off = 128; off; off >>= 1) {
        if (tid < off) { sl[tid] += sl[tid + off]; sc[tid] += sc[tid + off]; }
        __syncthreads();
    }
    if (tid == 0) out[0] = -(sl[0] / sc[0]);
}

// ---------------------------------------------------------------------------
// Fallback (bf16 on-the-fly convert) — only if ws too small
// ---------------------------------------------------------------------------
__global__ __launch_bounds__(256, 2) void nce_gemm_fb(
    const float* __restrict__ x, const float* __restrict__ emb,
    float* __restrict__ numer, float* __restrict__ pm, float* __restrict__ ps)
{
    __shared__ ushort At[BM][LDW];
    __shared__ ushort Bt[BN][LDW];

    const int rb = blockIdx.x, cs = blockIdx.y;
    const int row0 = rb * BM, col0 = cs * SLICE_W;
    const int tid = threadIdx.x, lane = tid & 63, wid = tid >> 6;
    const int wr = wid >> 1, wc = wid & 1, l15 = lane & 15, lhi = lane >> 4;

    float m_run[16], s_run[16];
#pragma unroll
    for (int i = 0; i < 16; ++i) { m_run[i] = -3.0e38f; s_run[i] = 0.0f; }

    for (int ct = 0; ct < CTS; ++ct) {
        const int colt0 = col0 + ct * BN;
        f32x4 acc[4][4];
#pragma unroll
        for (int a = 0; a < 4; ++a)
#pragma unroll
            for (int b = 0; b < 4; ++b) acc[a][b] = f32x4{0.f,0.f,0.f,0.f};

#pragma unroll 1
        for (int kt = 0; kt < KST; ++kt) {
            __syncthreads();
#pragma unroll
            for (int i = 0; i < 4; ++i) {
                const int chunk = tid + i * 256;
                const int r = chunk >> 3, c8 = (chunk & 7) << 3;
                const float* ga = emb + (size_t)(row0 + r) * D_DIM + kt * BK + c8;
                float4 a0 = *(const float4*)(ga); float4 a1 = *(const float4*)(ga + 4);
                uint4 pa;
                pa.x = pk2bf(a0.x, a0.y); pa.y = pk2bf(a0.z, a0.w);
                pa.z = pk2bf(a1.x, a1.y); pa.w = pk2bf(a1.z, a1.w);
                *(uint4*)&At[r][c8] = pa;
                const float* gb = x + (size_t)(colt0 + r) * D_DIM + kt * BK + c8;
                float4 b0 = *(const float4*)(gb); float4 b1 = *(const float4*)(gb + 4);
                uint4 pb;
                pb.x = pk2bf(b0.x, b0.y); pb.y = pk2bf(b0.z, b0.w);
                pb.z = pk2bf(b1.x, b1.y); pb.w = pk2bf(b1.z, b1.w);
                *(uint4*)&Bt[r][c8] = pb;
            }
            __syncthreads();
#pragma unroll
            for (int kp = 0; kp < 2; ++kp) {
                const int ko = kp * 32 + lhi * 8;
                bf16x8 af[4], bfr[4];
#pragma unroll
                for (int mi = 0; mi < 4; ++mi)
                    af[mi] = *(const bf16x8*)&At[wr*64 + mi*16 + l15][ko];
#pragma unroll
                for (int ni = 0; ni < 4; ++ni)
                    bfr[ni] = *(const bf16x8*)&Bt[wc*64 + ni*16 + l15][ko];
#pragma unroll
                for (int mi = 0; mi < 4; ++mi)
#pragma unroll
                    for (int ni = 0; ni < 4; ++ni)
                        acc[mi][ni] = __builtin_amdgcn_mfma_f32_16x16x32_bf16(
                            af[mi], bfr[ni], acc[mi][ni], 0, 0, 0);
            }
        }

#pragma unroll
        for (int mi = 0; mi < 4; ++mi)
#pragma unroll
            for (int r = 0; r < 4; ++r) {
                const int row_g = row0 + wr*64 + mi*16 + lhi*4 + r;
#pragma unroll
                for (int ni = 0; ni < 4; ++ni) {
                    const int col_g = colt0 + wc*64 + ni*16 + l15;
                    if (row_g == col_g) numer[row_g] = acc[mi][ni][r];
                }
                const int idx = mi * 4 + r;
                const float v0 = acc[mi][0][r], v1 = acc[mi][1][r];
                const float v2 = acc[mi][2][r], v3 = acc[mi][3][r];
                const float mx = fmaxf(fmaxf(v0, v1), fmaxf(v2, v3));
                const float mn = fmaxf(m_run[idx], mx);
                const float scale = __expf(m_run[idx] - mn);
                s_run[idx] = s_run[idx] * scale
                           + __expf(v0 - mn) + __expf(v1 - mn)
                           + __expf(v2 - mn) + __expf(v3 - mn);
                m_run[idx] = mn;
            }
    }

#pragma unroll
    for (int idx = 0; idx < 16; ++idx) {
        float m = m_run[idx], s = s_run[idx];
#pragma unroll
        for (int off = 1; off < 16; off <<= 1) {
            const float mo = __shfl_xor(m, off, 64);
            const float so = __shfl_xor(s, off, 64);
            const float mn = fmaxf(m, mo);
            s = s * __expf(m - mn) + so * __expf(mo - mn);
            m = mn;
        }
        m_run[idx] = m; s_run[idx] = s;
    }

    if (l15 == 0) {
        const int slot = cs * 2 + wc;
#pragma unroll
        for (int mi = 0; mi < 4; ++mi)
#pragma unroll
            for (int r = 0; r < 4; ++r) {
                const int row_g = row0 + wr*64 + mi*16 + lhi*4 + r;
                pm[row_g * NPART_FB + slot] = m_run[mi*4 + r];
                ps[row_g * NPART_FB + slot] = s_run[mi*4 + r];
            }
    }
}

extern "C" void kernel_launch(void* const* d_in, const int* in_sizes, int n_in,
                              void* d_out, int out_size, void* d_ws, size_t ws_size,
                              hipStream_t stream) {
    (void)in_sizes; (void)n_in; (void)out_size;
    const float* x   = (const float*)d_in[0];
    const float* emb = (const float*)d_in[1];
    const int*   tgt = (const int*)d_in[2];
    float* out = (float*)d_out;

    const size_t elems = (size_t)N_TOK * D_DIM;
    const size_t need  = elems * 2
                       + (size_t)N_TOK * 4
                       + (size_t)N_TOK * NPART3 * 4 * 2
                       + FIN_BLOCKS * 8;

    if (ws_size >= need) {
        unsigned char* xb8 = (unsigned char*)d_ws;
        unsigned char* eb8 = xb8 + elems;
        float* numer = (float*)(eb8 + elems);
        float* pm    = numer + N_TOK;
        float* ps    = pm + (size_t)N_TOK * NPART3;
        float* bl    = ps + (size_t)N_TOK * NPART3;
        float* bc    = bl + FIN_BLOCKS;

        conv_fp8<<<1024, 256, 0, stream>>>(x, emb, xb8, eb8);
        nce_gemm_mx<<<NSL3 * NSL3, 256, 0, stream>>>(xb8, eb8, numer, pm, ps);
        nce_finish_a<<<FIN_BLOCKS, 256, 0, stream>>>(tgt, numer, pm, ps, bl, bc, NPART3);
        nce_finish_b<<<1, 256, 0, stream>>>(bl, bc, out, FIN_BLOCKS);
    } else {
        float* numer = (float*)d_ws;
        float* pm    = numer + N_TOK;
        float* ps    = pm + (size_t)N_TOK * NPART_FB;
        float* bl    = ps + (size_t)N_TOK * NPART_FB;
        float* bc    = bl + FIN_BLOCKS;
        nce_gemm_fb<<<dim3(N_TOK / BM, NSLICE_FB), 256, 0, stream>>>(x, emb, numer, pm, ps);
        nce_finish_a<<<FIN_BLOCKS, 256, 0, stream>>>(tgt, numer, pm, ps, bl, bc, NPART_FB);
        nce_finish_b<<<1, 256, 0, stream>>>(bl, bc, out, FIN_BLOCKS);
    }
}

// Round 12
// 65.748 us; speedup vs baseline: 2.4561x; 1.0083x over previous
//
#include <hip/hip_runtime.h>
#include <hip/hip_bf16.h>
#include <stdint.h>

// Problem constants (B=8, S=512, D=1024)
constexpr int N_TOK  = 4096;   // B*S
constexpr int D_DIM  = 1024;
constexpr int MASK_ID_V = 8192;

// Fast path: m201-style 256x256 tile, 8 waves (2Mx4N, 128x64 per wave),
// BK=64, 4 fine phases per K-tile, dbuf LDS in M/N halves, counted vmcnt
constexpr int BM2  = 256;
constexpr int KT2  = D_DIM / 64;     // 16 K-tiles
constexpr int NSL2 = N_TOK / BM2;    // 16 col slices
constexpr int NPART = NSL2 * 4;      // 64 partials/row (4 wc-waves per slice)

// Fallback tiling (used only if ws too small)
constexpr int BM = 128, BN = 128, BK = 64;
constexpr int KST = D_DIM / BK;
constexpr int NSLICE_FB = 8;
constexpr int SLICE_W   = N_TOK / NSLICE_FB;
constexpr int CTS       = SLICE_W / BN;
constexpr int LDW       = BK + 8;
constexpr int NPART_FB  = NSLICE_FB * 2;

constexpr int FIN_BLOCKS = 256;

typedef __attribute__((ext_vector_type(4))) float f32x4;
typedef __attribute__((ext_vector_type(8))) short bf16x8;

__device__ __forceinline__ uint32_t pk2bf(float lo, float hi) {
    union { float f; uint32_t u; } a, b;
    a.f = lo; b.f = hi;
    uint32_t ua = (a.u + 0x7fffu + ((a.u >> 16) & 1u)) >> 16;
    uint32_t ub = (b.u + 0x7fffu + ((b.u >> 16) & 1u)) >> 16;
    return ua | (ub << 16);
}

__device__ __forceinline__ void async16(void* lds, const void* g) {
    __builtin_amdgcn_global_load_lds(
        (const __attribute__((address_space(1))) uint32_t*)g,
        (__attribute__((address_space(3))) uint32_t*)lds,
        16, 0, 0);
}

#define BAR do { __builtin_amdgcn_s_barrier(); __builtin_amdgcn_sched_barrier(0); } while (0)

// ---------------------------------------------------------------------------
// Pass 1: fp32 -> bf16 pre-convert (once)
// ---------------------------------------------------------------------------
__global__ __launch_bounds__(256) void conv_bf16(
    const float* __restrict__ x, const float* __restrict__ e,
    ushort* __restrict__ xb, ushort* __restrict__ eb)
{
    constexpr int NCHUNK = N_TOK * D_DIM / 8;
    const int t0 = blockIdx.x * blockDim.x + threadIdx.x;
    const int stride = gridDim.x * blockDim.x;
    for (int c = t0; c < NCHUNK; c += stride) {
        float4 a0 = ((const float4*)x)[c * 2];
        float4 a1 = ((const float4*)x)[c * 2 + 1];
        uint4 p;
        p.x = pk2bf(a0.x, a0.y); p.y = pk2bf(a0.z, a0.w);
        p.z = pk2bf(a1.x, a1.y); p.w = pk2bf(a1.z, a1.w);
        ((uint4*)xb)[c] = p;

        float4 b0 = ((const float4*)e)[c * 2];
        float4 b1 = ((const float4*)e)[c * 2 + 1];
        uint4 q;
        q.x = pk2bf(b0.x, b0.y); q.y = pk2bf(b0.z, b0.w);
        q.z = pk2bf(b1.x, b1.y); q.w = pk2bf(b1.z, b1.w);
        ((uint4*)eb)[c] = q;
    }
}

// ---------------------------------------------------------------------------
// Pass 2: bf16 GEMM, 4 fine phases per K-tile (m201 structure) + online lse
// ---------------------------------------------------------------------------
__global__ __launch_bounds__(512, 2) void nce_gemm_8p(
    const ushort* __restrict__ xb,    // [N_TOK][1024] bf16 keys
    const ushort* __restrict__ eb,    // [N_TOK][1024] bf16 queries
    float* __restrict__ numer,
    float* __restrict__ pm,
    float* __restrict__ ps)
{
    __shared__ ushort As[2][2][8192];   // [buf][Mhalf][128 rows][64 cols] 64 KB
    __shared__ ushort Bs[2][2][8192];   // [buf][Nhalf]                    64 KB

    // Bijective XCD-chunked swizzle: each XCD -> two 4x4 tile-chunks
    const int bid  = blockIdx.x;
    const int sw_  = (bid & 7) * 32 + (bid >> 3);
    const int ch   = sw_ >> 4, win = sw_ & 15;
    const int rb   = (ch & 3) * 4 + (win & 3);
    const int cs   = (ch >> 2) * 4 + (win >> 2);
    const int row0 = rb * BM2;
    const int col0 = cs * BM2;

    const int tid  = threadIdx.x;
    const int lane = tid & 63;
    const int wid  = tid >> 6;         // 0..7
    const int wr   = wid >> 2;         // 0..1  (M-warp: rows wr*128..+127)
    const int wc   = wid & 3;          // 0..3  (N-warp: cols wc*64..+63)
    const int l15  = lane & 15;
    const int lhi  = lane >> 4;        // 0..3
    const int bh   = wc >> 1;          // B half this wave reads

    // Staging: half-tile = 128 rows x 64 bf16 = 1024 chunks of 16B; wave
    // covers chunks wid*128..+127 via two wave-instrs. Linear LDS dest;
    // source slot = (q&7) ^ (row&7)  [involution swizzle, both sides]
    const int q0 = wid * 128 + lane, q1 = q0 + 64;
    const int r0 = q0 >> 3, sc0 = (q0 & 7) ^ (r0 & 7);
    const int r1 = q1 >> 3, sc1 = (q1 & 7) ^ (r1 & 7);
    const ushort* pA00 = eb + (size_t)(row0 +       r0) * D_DIM + sc0 * 8;
    const ushort* pA01 = eb + (size_t)(row0 +       r1) * D_DIM + sc1 * 8;
    const ushort* pA10 = eb + (size_t)(row0 + 128 + r0) * D_DIM + sc0 * 8;
    const ushort* pA11 = eb + (size_t)(row0 + 128 + r1) * D_DIM + sc1 * 8;
    const ushort* pB00 = xb + (size_t)(col0 +       r0) * D_DIM + sc0 * 8;
    const ushort* pB01 = xb + (size_t)(col0 +       r1) * D_DIM + sc1 * 8;
    const ushort* pB10 = xb + (size_t)(col0 + 128 + r0) * D_DIM + sc0 * 8;
    const ushort* pB11 = xb + (size_t)(col0 + 128 + r1) * D_DIM + sc1 * 8;
    const int dB = wid * 1024;          // ushort offset of wave's chunk region

#define STG(base_, P0_, P1_) do { \
    async16((void*)((base_) + dB),       (P0_)); \
    async16((void*)((base_) + dB + 512), (P1_)); } while (0)

    // Frag read offsets (ushort units). Row stride 64 ushorts (128 B);
    // slot = (ks*4 + lhi) ^ (localrow & 7); localrow&7 == l15&7 always.
    const int sw8  = l15 & 7;
    const int oA0  = l15 * 64 + (((0 + lhi) ^ sw8) * 8);
    const int oA1  = l15 * 64 + (((4 + lhi) ^ sw8) * 8);
    const int bRow = (wc & 1) * 64 + l15;
    const int oB0  = bRow * 64 + (((0 + lhi) ^ sw8) * 8);
    const int oB1  = bRow * 64 + (((4 + lhi) ^ sw8) * 8);

    f32x4 acc[8][4];
#pragma unroll
    for (int a = 0; a < 8; ++a)
#pragma unroll
        for (int b = 0; b < 4; ++b)
            acc[a][b] = f32x4{0.f, 0.f, 0.f, 0.f};

    // Prologue: stage K-tile 0's four half-tiles into buf 0 (order A0,A1,B0,B1)
    STG(&As[0][0][0], pA00, pA01);
    STG(&As[0][1][0], pA10, pA11);
    STG(&Bs[0][0][0], pB00, pB01);
    STG(&Bs[0][1][0], pB10, pB11);

#pragma unroll 1
    for (int kt = 0; kt < KT2; ++kt) {
        const int c = kt & 1, n = c ^ 1;
        const bool pre = (kt < KT2 - 1);
        const int ko = (kt + 1) * 64;          // ushort advance to next K-tile

        const ushort* Ab = &As[c][wr][0];
        const ushort* Bb = &Bs[c][bh][0];

        bf16x8 af[4][2], bq[4][2];

        // ---- P0: stage A-half0(kt+1); validate tile kt; quad (m0..3, n0..1)
        if (pre) {
            STG(&As[n][0][0], pA00 + ko, pA01 + ko);
            asm volatile("s_waitcnt vmcnt(2)" ::: "memory");  // all of kt landed
        } else {
            asm volatile("s_waitcnt vmcnt(0)" ::: "memory");
        }
        __builtin_amdgcn_sched_barrier(0);
        BAR;
#pragma unroll
        for (int mf = 0; mf < 4; ++mf) {
            af[mf][0] = *(const bf16x8*)(Ab + mf * 1024 + oA0);
            af[mf][1] = *(const bf16x8*)(Ab + mf * 1024 + oA1);
        }
#pragma unroll
        for (int nf = 0; nf < 2; ++nf) {
            bq[nf][0] = *(const bf16x8*)(Bb + nf * 1024 + oB0);
            bq[nf][1] = *(const bf16x8*)(Bb + nf * 1024 + oB1);
        }
        __builtin_amdgcn_s_setprio(1);
#pragma unroll
        for (int mf = 0; mf < 4; ++mf)
#pragma unroll
            for (int nf = 0; nf < 2; ++nf) {
                acc[mf][nf] = __builtin_amdgcn_mfma_f32_16x16x32_bf16(
                    af[mf][0], bq[nf][0], acc[mf][nf], 0, 0, 0);
                acc[mf][nf] = __builtin_amdgcn_mfma_f32_16x16x32_bf16(
                    af[mf][1], bq[nf][1], acc[mf][nf], 0, 0, 0);
            }
        __builtin_amdgcn_s_setprio(0);
        BAR;

        // ---- P1: stage A-half1(kt+1); quad (m0..3, n2..3)
        if (pre) STG(&As[n][1][0], pA10 + ko, pA11 + ko);
#pragma unroll
        for (int nf = 2; nf < 4; ++nf) {
            bq[nf][0] = *(const bf16x8*)(Bb + nf * 1024 + oB0);
            bq[nf][1] = *(const bf16x8*)(Bb + nf * 1024 + oB1);
        }
        __builtin_amdgcn_s_setprio(1);
#pragma unroll
        for (int mf = 0; mf < 4; ++mf)
#pragma unroll
            for (int nf = 2; nf < 4; ++nf) {
                acc[mf][nf] = __builtin_amdgcn_mfma_f32_16x16x32_bf16(
                    af[mf][0], bq[nf][0], acc[mf][nf], 0, 0, 0);
                acc[mf][nf] = __builtin_amdgcn_mfma_f32_16x16x32_bf16(
                    af[mf][1], bq[nf][1], acc[mf][nf], 0, 0, 0);
            }
        __builtin_amdgcn_s_setprio(0);
        BAR;

        // ---- P2: stage B-half0(kt+1); quad (m4..7, n0..1)
        if (pre) STG(&Bs[n][0][0], pB00 + ko, pB01 + ko);
#pragma unroll
        for (int mf = 0; mf < 4; ++mf) {
            af[mf][0] = *(const bf16x8*)(Ab + (4 + mf) * 1024 + oA0);
            af[mf][1] = *(const bf16x8*)(Ab + (4 + mf) * 1024 + oA1);
        }
        __builtin_amdgcn_s_setprio(1);
#pragma unroll
        for (int mf = 0; mf < 4; ++mf)
#pragma unroll
            for (int nf = 0; nf < 2; ++nf) {
                acc[4 + mf][nf] = __builtin_amdgcn_mfma_f32_16x16x32_bf16(
                    af[mf][0], bq[nf][0], acc[4 + mf][nf], 0, 0, 0);
                acc[4 + mf][nf] = __builtin_amdgcn_mfma_f32_16x16x32_bf16(
                    af[mf][1], bq[nf][1], acc[4 + mf][nf], 0, 0, 0);
            }
        __builtin_amdgcn_s_setprio(0);
        BAR;

        // ---- P3: stage B-half1(kt+1); quad (m4..7, n2..3)
        if (pre) STG(&Bs[n][1][0], pB10 + ko, pB11 + ko);
        __builtin_amdgcn_s_setprio(1);
#pragma unroll
        for (int mf = 0; mf < 4; ++mf)
#pragma unroll
            for (int nf = 2; nf < 4; ++nf) {
                acc[4 + mf][nf] = __builtin_amdgcn_mfma_f32_16x16x32_bf16(
                    af[mf][0], bq[nf][0], acc[4 + mf][nf], 0, 0, 0);
                acc[4 + mf][nf] = __builtin_amdgcn_mfma_f32_16x16x32_bf16(
                    af[mf][1], bq[nf][1], acc[4 + mf][nf], 0, 0, 0);
            }
        __builtin_amdgcn_s_setprio(0);
        BAR;
    }
#undef STG

    // Epilogue: diagonal + per-(mf,r) softmax partial + 16-lane butterfly
#pragma unroll
    for (int mf = 0; mf < 8; ++mf)
#pragma unroll
        for (int r = 0; r < 4; ++r) {
            const int row_g = row0 + wr * 128 + mf * 16 + lhi * 4 + r;
#pragma unroll
            for (int nf = 0; nf < 4; ++nf) {
                const int col_g = col0 + wc * 64 + nf * 16 + l15;
                if (row_g == col_g) numer[row_g] = acc[mf][nf][r];
            }
            const float v0 = acc[mf][0][r], v1 = acc[mf][1][r];
            const float v2 = acc[mf][2][r], v3 = acc[mf][3][r];
            float m = fmaxf(fmaxf(v0, v1), fmaxf(v2, v3));
            float s = __expf(v0 - m) + __expf(v1 - m)
                    + __expf(v2 - m) + __expf(v3 - m);
#pragma unroll
            for (int off = 1; off < 16; off <<= 1) {
                const float mo = __shfl_xor(m, off, 64);
                const float so = __shfl_xor(s, off, 64);
                const float mn = fmaxf(m, mo);
                s = s * __expf(m - mn) + so * __expf(mo - mn);
                m = mn;
            }
            if (l15 == 0) {
                pm[row_g * NPART + cs * 4 + wc] = m;
                ps[row_g * NPART + cs * 4 + wc] = s;
            }
        }
}

// ---------------------------------------------------------------------------
// Pass 3a: one WAVE per row — coalesced partial combine + masked row loss
// ---------------------------------------------------------------------------
__global__ __launch_bounds__(256) void nce_finish_a(
    const int* __restrict__ tgt,
    const float* __restrict__ numer,
    const float* __restrict__ pm,
    const float* __restrict__ ps,
    float* __restrict__ bl_loss,
    float* __restrict__ bl_cnt,
    int npart)
{
    const int tid  = threadIdx.x;
    const int lane = tid & 63;
    const int wv   = tid >> 6;
    const int waves_total = gridDim.x * 4;

    float loss = 0.f, cnt = 0.f;

    for (int row = blockIdx.x * 4 + wv; row < N_TOK; row += waves_total) {
        if (tgt[row] != MASK_ID_V) continue;
        float pmv = -3.0e38f, psv = 0.f;
        if (lane < npart) {
            pmv = pm[row * npart + lane];
            psv = ps[row * npart + lane];
        }
        float m = pmv;
#pragma unroll
        for (int off = 32; off; off >>= 1) m = fmaxf(m, __shfl_xor(m, off, 64));
        float sv = psv * __expf(pmv - m);
#pragma unroll
        for (int off = 32; off; off >>= 1) sv += __shfl_xor(sv, off, 64);
        if (lane == 0) {
            loss += numer[row] - (m + __logf(sv));
            cnt  += 1.f;
        }
    }

    __shared__ float sl[4], sc[4];
    if (lane == 0) { sl[wv] = loss; sc[wv] = cnt; }
    __syncthreads();
    if (tid == 0) {
        bl_loss[blockIdx.x] = sl[0] + sl[1] + sl[2] + sl[3];
        bl_cnt[blockIdx.x]  = sc[0] + sc[1] + sc[2] + sc[3];
    }
}

__global__ __launch_bounds__(256) void nce_finish_b(
    const float* __restrict__ bl_loss,
    const float* __restrict__ bl_cnt,
    float* __restrict__ out, int nblk)
{
    const int tid = threadIdx.x;
    float l = 0.f, c = 0.f;
    for (int i = tid; i < nblk; i += 256) { l += bl_loss[i]; c += bl_cnt[i]; }
    __shared__ float sl[256], sc[256];
    sl[tid] = l; sc[tid] = c;
    __syncthreads();
    for (int off = 128; off; off >>= 1) {
        if (tid < off) { sl[tid] += sl[tid + off]; sc[tid] += sc[tid + off]; }
        __syncthreads();
    }
    if (tid == 0) out[0] = -(sl[0] / sc[0]);
}

// ---------------------------------------------------------------------------
// Fallback (bf16 on-the-fly convert) — only if ws too small
// ---------------------------------------------------------------------------
__global__ __launch_bounds__(256, 2) void nce_gemm_fb(
    const float* __restrict__ x, const float* __restrict__ emb,
    float* __restrict__ numer, float* __restrict__ pm, float* __restrict__ ps)
{
    __shared__ ushort At[BM][LDW];
    __shared__ ushort Bt[BN][LDW];

    const int rb = blockIdx.x, cs = blockIdx.y;
    const int row0 = rb * BM, col0 = cs * SLICE_W;
    const int tid = threadIdx.x, lane = tid & 63, wid = tid >> 6;
    const int wr = wid >> 1, wc = wid & 1, l15 = lane & 15, lhi = lane >> 4;

    float m_run[16], s_run[16];
#pragma unroll
    for (int i = 0; i < 16; ++i) { m_run[i] = -3.0e38f; s_run[i] = 0.0f; }

    for (int ct = 0; ct < CTS; ++ct) {
        const int colt0 = col0 + ct * BN;
        f32x4 acc[4][4];
#pragma unroll
        for (int a = 0; a < 4; ++a)
#pragma unroll
            for (int b = 0; b < 4; ++b) acc[a][b] = f32x4{0.f,0.f,0.f,0.f};

#pragma unroll 1
        for (int kt = 0; kt < KST; ++kt) {
            __syncthreads();
#pragma unroll
            for (int i = 0; i < 4; ++i) {
                const int chunk = tid + i * 256;
                const int r = chunk >> 3, c8 = (chunk & 7) << 3;
                const float* ga = emb + (size_t)(row0 + r) * D_DIM + kt * BK + c8;
                float4 a0 = *(const float4*)(ga); float4 a1 = *(const float4*)(ga + 4);
                uint4 pa;
                pa.x = pk2bf(a0.x, a0.y); pa.y = pk2bf(a0.z, a0.w);
                pa.z = pk2bf(a1.x, a1.y); pa.w = pk2bf(a1.z, a1.w);
                *(uint4*)&At[r][c8] = pa;
                const float* gb = x + (size_t)(colt0 + r) * D_DIM + kt * BK + c8;
                float4 b0 = *(const float4*)(gb); float4 b1 = *(const float4*)(gb + 4);
                uint4 pb;
                pb.x = pk2bf(b0.x, b0.y); pb.y = pk2bf(b0.z, b0.w);
                pb.z = pk2bf(b1.x, b1.y); pb.w = pk2bf(b1.z, b1.w);
                *(uint4*)&Bt[r][c8] = pb;
            }
            __syncthreads();
#pragma unroll
            for (int kp = 0; kp < 2; ++kp) {
                const int ko = kp * 32 + lhi * 8;
                bf16x8 af[4], bfr[4];
#pragma unroll
                for (int mi = 0; mi < 4; ++mi)
                    af[mi] = *(const bf16x8*)&At[wr*64 + mi*16 + l15][ko];
#pragma unroll
                for (int ni = 0; ni < 4; ++ni)
                    bfr[ni] = *(const bf16x8*)&Bt[wc*64 + ni*16 + l15][ko];
#pragma unroll
                for (int mi = 0; mi < 4; ++mi)
#pragma unroll
                    for (int ni = 0; ni < 4; ++ni)
                        acc[mi][ni] = __builtin_amdgcn_mfma_f32_16x16x32_bf16(
                            af[mi], bfr[ni], acc[mi][ni], 0, 0, 0);
            }
        }

#pragma unroll
        for (int mi = 0; mi < 4; ++mi)
#pragma unroll
            for (int r = 0; r < 4; ++r) {
                const int row_g = row0 + wr*64 + mi*16 + lhi*4 + r;
#pragma unroll
                for (int ni = 0; ni < 4; ++ni) {
                    const int col_g = colt0 + wc*64 + ni*16 + l15;
                    if (row_g == col_g) numer[row_g] = acc[mi][ni][r];
                }
                const int idx = mi * 4 + r;
                const float v0 = acc[mi][0][r], v1 = acc[mi][1][r];
                const float v2 = acc[mi][2][r], v3 = acc[mi][3][r];
                const float mx = fmaxf(fmaxf(v0, v1), fmaxf(v2, v3));
                const float mn = fmaxf(m_run[idx], mx);
                const float scale = __expf(m_run[idx] - mn);
                s_run[idx] = s_run[idx] * scale
                           + __expf(v0 - mn) + __expf(v1 - mn)
                           + __expf(v2 - mn) + __expf(v3 - mn);
                m_run[idx] = mn;
            }
    }

#pragma unroll
    for (int idx = 0; idx < 16; ++idx) {
        float m = m_run[idx], s = s_run[idx];
#pragma unroll
        for (int off = 1; off < 16; off <<= 1) {
            const float mo = __shfl_xor(m, off, 64);
            const float so = __shfl_xor(s, off, 64);
            const float mn = fmaxf(m, mo);
            s = s * __expf(m - mn) + so * __expf(mo - mn);
            m = mn;
        }
        m_run[idx] = m; s_run[idx] = s;
    }

    if (l15 == 0) {
        const int slot = cs * 2 + wc;
#pragma unroll
        for (int mi = 0; mi < 4; ++mi)
#pragma unroll
            for (int r = 0; r < 4; ++r) {
                const int row_g = row0 + wr*64 + mi*16 + lhi*4 + r;
                pm[row_g * NPART_FB + slot] = m_run[mi*4 + r];
                ps[row_g * NPART_FB + slot] = s_run[mi*4 + r];
            }
    }
}

extern "C" void kernel_launch(void* const* d_in, const int* in_sizes, int n_in,
                              void* d_out, int out_size, void* d_ws, size_t ws_size,
                              hipStream_t stream) {
    (void)in_sizes; (void)n_in; (void)out_size;
    const float* x   = (const float*)d_in[0];
    const float* emb = (const float*)d_in[1];
    const int*   tgt = (const int*)d_in[2];
    float* out = (float*)d_out;

    const size_t elems = (size_t)N_TOK * D_DIM;
    const size_t need  = elems * 2 * 2                 // xb + eb (bf16)
                       + (size_t)N_TOK * 4             // numer
                       + (size_t)N_TOK * NPART * 4 * 2 // pm + ps
                       + FIN_BLOCKS * 8;

    if (ws_size >= need) {
        ushort* xb    = (ushort*)d_ws;
        ushort* eb    = xb + elems;
        float*  numer = (float*)(eb + elems);
        float*  pm    = numer + N_TOK;
        float*  ps    = pm + (size_t)N_TOK * NPART;
        float*  bl    = ps + (size_t)N_TOK * NPART;
        float*  bc    = bl + FIN_BLOCKS;

        conv_bf16<<<1024, 256, 0, stream>>>(x, emb, xb, eb);
        nce_gemm_8p<<<NSL2 * NSL2, 512, 0, stream>>>(xb, eb, numer, pm, ps);
        nce_finish_a<<<FIN_BLOCKS, 256, 0, stream>>>(tgt, numer, pm, ps, bl, bc, NPART);
        nce_finish_b<<<1, 256, 0, stream>>>(bl, bc, out, FIN_BLOCKS);
    } else {
        float* numer = (float*)d_ws;
        float* pm    = numer + N_TOK;
        float* ps    = pm + (size_t)N_TOK * NPART_FB;
        float* bl    = ps + (size_t)N_TOK * NPART_FB;
        float* bc    = bl + FIN_BLOCKS;
        nce_gemm_fb<<<dim3(N_TOK / BM, NSLICE_FB), 256, 0, stream>>>(x, emb, numer, pm, ps);
        nce_finish_a<<<FIN_BLOCKS, 256, 0, stream>>>(tgt, numer, pm, ps, bl, bc, NPART_FB);
        nce_finish_b<<<1, 256, 0, stream>>>(bl, bc, out, FIN_BLOCKS);
    }
}

// Round 13
// 50.502 us; speedup vs baseline: 3.1976x; 1.3019x over previous
//
#include <hip/hip_runtime.h>
#include <hip/hip_bf16.h>
#include <stdint.h>

// Problem constants (B=8, S=512, D=1024)
constexpr int N_TOK  = 4096;   // B*S
constexpr int D_DIM  = 1024;
constexpr int MASK_ID_V = 8192;

// Fast path: 256x256 tiles, 16 waves (4Mx4N, 64x64/wave), fp8 MX 32x32x64,
// BK=128 per iter (8 iters), dbuf LDS, FRAGMENT-ORDER layout (conflict-free)
constexpr int BM2  = 256;
constexpr int KIT  = D_DIM / 128;    // 8 K-iters
constexpr int NSL2 = N_TOK / BM2;    // 16 col slices
constexpr int NPART = NSL2 * 4;      // 64 partials/row

constexpr float SCALE   = 64.0f;     // pre-scale into e4m3 normal range
constexpr float INVSC2  = 1.0f / (SCALE * SCALE);

// Fallback tiling (used only if ws too small)
constexpr int BM = 128, BN = 128, BK = 64;
constexpr int KST = D_DIM / BK;
constexpr int NSLICE_FB = 8;
constexpr int SLICE_W   = N_TOK / NSLICE_FB;
constexpr int CTS       = SLICE_W / BN;
constexpr int LDW       = BK + 8;
constexpr int NPART_FB  = NSLICE_FB * 2;

constexpr int FIN_BLOCKS = 256;

typedef __attribute__((ext_vector_type(4)))  float f32x4;
typedef __attribute__((ext_vector_type(16))) float f32x16;
typedef __attribute__((ext_vector_type(8)))  short bf16x8;
typedef __attribute__((ext_vector_type(8)))  int   i32x8;

__device__ __forceinline__ uint32_t pk2bf(float lo, float hi) {
    union { float f; uint32_t u; } a, b;
    a.f = lo; b.f = hi;
    uint32_t ua = (a.u + 0x7fffu + ((a.u >> 16) & 1u)) >> 16;
    uint32_t ub = (b.u + 0x7fffu + ((b.u >> 16) & 1u)) >> 16;
    return ua | (ub << 16);
}

__device__ __forceinline__ void async16(void* lds, const void* g) {
    __builtin_amdgcn_global_load_lds(
        (const __attribute__((address_space(1))) uint32_t*)g,
        (__attribute__((address_space(3))) uint32_t*)lds,
        16, 0, 0);
}

#define BAR do { __builtin_amdgcn_s_barrier(); __builtin_amdgcn_sched_barrier(0); } while (0)

// ---------------------------------------------------------------------------
// Pass 1: fp32 -> fp8 e4m3 pre-convert, output in MFMA-FRAGMENT-CHUNK order.
// Chunk id = (R*8 + kt)*4 + ks*2 + j   (R = row/32, kt = col/128,
// ks = (col>>6)&1, j = (col>>4)&1); within a 1KB chunk, lane = (col>>5 &1)*32
// + (row&31) holds 16 bytes. gemm staging then fetches contiguous 1KB chunks.
// ---------------------------------------------------------------------------
__device__ __forceinline__ uint pk4fp8(float4 v) {
    int w = __builtin_amdgcn_cvt_pk_fp8_f32(v.x * SCALE, v.y * SCALE, 0, false);
    w = __builtin_amdgcn_cvt_pk_fp8_f32(v.z * SCALE, v.w * SCALE, w, true);
    return (uint)w;
}

__global__ __launch_bounds__(256) void conv_fp8_frag(
    const float* __restrict__ x, const float* __restrict__ e,
    unsigned char* __restrict__ xb8, unsigned char* __restrict__ eb8)
{
    constexpr int NT = N_TOK * 64;        // tasks: (row, 16-float chunk)
    const int t0 = blockIdx.x * blockDim.x + threadIdx.x;
    const int stride = gridDim.x * blockDim.x;
    for (int t = t0; t < NT; t += stride) {
        const int r   = t >> 6;           // source row (reads coalesced)
        const int c16 = t & 63;           // 16-float chunk within row
        const int R   = r >> 5;
        const int kt  = c16 >> 3;
        const int ks  = (c16 >> 2) & 1;
        const int lg  = (c16 >> 1) & 1;
        const int j   = c16 & 1;
        const int lane = lg * 32 + (r & 31);
        const size_t off =
            (((size_t)(R * 8 + kt) * 4 + ks * 2 + j) * 64 + lane) * 16;

        const float* sx = x + (size_t)r * D_DIM + c16 * 16;
        uint4 o;
        o.x = pk4fp8(*(const float4*)(sx));
        o.y = pk4fp8(*(const float4*)(sx + 4));
        o.z = pk4fp8(*(const float4*)(sx + 8));
        o.w = pk4fp8(*(const float4*)(sx + 12));
        *(uint4*)(xb8 + off) = o;

        const float* se = e + (size_t)r * D_DIM + c16 * 16;
        uint4 q;
        q.x = pk4fp8(*(const float4*)(se));
        q.y = pk4fp8(*(const float4*)(se + 4));
        q.z = pk4fp8(*(const float4*)(se + 8));
        q.w = pk4fp8(*(const float4*)(se + 12));
        *(uint4*)(eb8 + off) = q;
    }
}

// ---------------------------------------------------------------------------
// Pass 2: fp8 MX GEMM — r8 loop skeleton + fragment-order LDS (linear reads)
// ---------------------------------------------------------------------------
__device__ __forceinline__ i32x8 ld_frag(const unsigned char* base) {
    uint4 u = *(const uint4*)(base);          // j=0 chunk
    uint4 v = *(const uint4*)(base + 1024);   // j=1 chunk
    i32x8 r = { (int)u.x, (int)u.y, (int)u.z, (int)u.w,
                (int)v.x, (int)v.y, (int)v.z, (int)v.w };
    return r;
}

#define MFMA8(A_, B_, C_) __builtin_amdgcn_mfma_scale_f32_32x32x64_f8f6f4( \
    A_, B_, C_, 0, 0, 0, 127, 0, 127)

__global__ __launch_bounds__(1024, 4) void nce_gemm_fp8f(
    const unsigned char* __restrict__ xb8,   // frag-ordered fp8 keys (x*64)
    const unsigned char* __restrict__ eb8,   // frag-ordered fp8 queries
    float* __restrict__ numer,
    float* __restrict__ pm,
    float* __restrict__ ps)
{
    __shared__ unsigned char As[2][32768];   // [buf][32 chunks x 1KB]
    __shared__ unsigned char Bs[2][32768];   // total 128 KB

    // Bijective XCD-chunked swizzle: each XCD -> two 4x4 tile-chunks
    const int bid = blockIdx.x;
    const int sw_ = (bid & 7) * 32 + (bid >> 3);
    const int chv = sw_ >> 4, win = sw_ & 15;
    const int rb  = (chv & 3) * 4 + (win & 3);
    const int cs  = (chv >> 2) * 4 + (win >> 2);
    const int row0 = rb * BM2;
    const int col0 = cs * BM2;

    const int tid  = threadIdx.x;
    const int lane = tid & 63;
    const int wid  = tid >> 6;         // 0..15
    const int wr   = wid >> 2;         // 0..3  (M-warps, 64 rows each)
    const int wc   = wid & 3;          // 0..3  (N-warps, 64 cols each)
    const int l31  = lane & 31;
    const int lg   = lane >> 5;        // 0..1

    // Staging: wave stages LDS chunks c0=wid*2, c1=wid*2+1 for A and B.
    // Source chunk id = (R_g*8 + kt)*4 + (c&3), R_g = tileblk*8 + (c>>2).
    // Contiguous 1KB per instruction (coalesced); LDS dest linear.
    const int c0 = wid * 2, c1 = c0 + 1;
    const unsigned char* sA0 = eb8 +
        (((size_t)(rb * 8 + (c0 >> 2)) * 8 * 4 + (c0 & 3)) * 1024) + lane * 16;
    const unsigned char* sA1 = eb8 +
        (((size_t)(rb * 8 + (c1 >> 2)) * 8 * 4 + (c1 & 3)) * 1024) + lane * 16;
    const unsigned char* sB0 = xb8 +
        (((size_t)(cs * 8 + (c0 >> 2)) * 8 * 4 + (c0 & 3)) * 1024) + lane * 16;
    const unsigned char* sB1 = xb8 +
        (((size_t)(cs * 8 + (c1 >> 2)) * 8 * 4 + (c1 & 3)) * 1024) + lane * 16;
    const int d0 = c0 * 1024, d1 = c1 * 1024;

    // Frag read bases: chunk ((wr*2+mloc)*4 + ks*2 + j)*1024 + lane*16.
    // mloc -> +4096, ks -> +2048, j -> +1024 (handled in ld_frag). Linear.
    const int aBase = wr * 2 * 4096 + lane * 16;
    const int bBase = wc * 2 * 4096 + lane * 16;

    f32x16 acc00, acc01, acc10, acc11;
#pragma unroll
    for (int i = 0; i < 16; ++i) { acc00[i] = 0.f; acc01[i] = 0.f; acc10[i] = 0.f; acc11[i] = 0.f; }

    // Prologue: stage K-iter 0 into buffer 0
    async16(As[0] + d0, sA0);
    async16(As[0] + d1, sA1);
    async16(Bs[0] + d0, sB0);
    async16(Bs[0] + d1, sB1);

#pragma unroll 1
    for (int kt = 0; kt < KIT; ++kt) {
        const int c = kt & 1, n = c ^ 1;

        asm volatile("s_waitcnt vmcnt(0)" ::: "memory");
        BAR;

        if (kt < KIT - 1) {
            const int adv = (kt + 1) * 4096;   // kt advance = 4 chunks
            async16(As[n] + d0, sA0 + adv);
            async16(As[n] + d1, sA1 + adv);
            async16(Bs[n] + d0, sB0 + adv);
            async16(Bs[n] + d1, sB1 + adv);
        }

        const unsigned char* Ab = As[c] + aBase;
        const unsigned char* Bb = Bs[c] + bBase;
#pragma unroll
        for (int ks = 0; ks < 2; ++ks) {
            i32x8 a0 = ld_frag(Ab + ks * 2048);
            i32x8 a1 = ld_frag(Ab + 4096 + ks * 2048);
            i32x8 b0 = ld_frag(Bb + ks * 2048);
            i32x8 b1 = ld_frag(Bb + 4096 + ks * 2048);
            __builtin_amdgcn_s_setprio(1);
            acc00 = MFMA8(a0, b0, acc00);
            acc01 = MFMA8(a0, b1, acc01);
            acc10 = MFMA8(a1, b0, acc10);
            acc11 = MFMA8(a1, b1, acc11);
            __builtin_amdgcn_s_setprio(0);
        }
    }

    // Epilogue (r8-verified). 32x32 C/D: col = lane&31,
    // row = (reg&3)+8*(reg>>2)+4*lg; mloc adds 32 rows.
    const int c0g = col0 + wc * 64 + l31;
    const int c1g = c0g + 32;

#pragma unroll
    for (int reg = 0; reg < 16; ++reg) {
        const int rif = (reg & 3) + 8 * (reg >> 2) + 4 * lg;
#pragma unroll
        for (int fr = 0; fr < 2; ++fr) {
            const int row_g = row0 + wr * 64 + fr * 32 + rif;
            const float v0 = (fr ? acc10[reg] : acc00[reg]) * INVSC2;
            const float v1 = (fr ? acc11[reg] : acc01[reg]) * INVSC2;
            if (row_g == c0g) numer[row_g] = v0;
            if (row_g == c1g) numer[row_g] = v1;
            float m = fmaxf(v0, v1);
#pragma unroll
            for (int off = 1; off <= 16; off <<= 1)
                m = fmaxf(m, __shfl_xor(m, off, 64));
            float s = __expf(v0 - m) + __expf(v1 - m);
#pragma unroll
            for (int off = 1; off <= 16; off <<= 1)
                s += __shfl_xor(s, off, 64);
            if (l31 == 0) {
                pm[row_g * NPART + cs * 4 + wc] = m;
                ps[row_g * NPART + cs * 4 + wc] = s;
            }
        }
    }
}

// ---------------------------------------------------------------------------
// Pass 3a: one WAVE per row — coalesced partial combine + masked row loss
// ---------------------------------------------------------------------------
__global__ __launch_bounds__(256) void nce_finish_a(
    const int* __restrict__ tgt,
    const float* __restrict__ numer,
    const float* __restrict__ pm,
    const float* __restrict__ ps,
    float* __restrict__ bl_loss,
    float* __restrict__ bl_cnt,
    int npart)
{
    const int tid  = threadIdx.x;
    const int lane = tid & 63;
    const int wv   = tid >> 6;
    const int waves_total = gridDim.x * 4;

    float loss = 0.f, cnt = 0.f;

    for (int row = blockIdx.x * 4 + wv; row < N_TOK; row += waves_total) {
        if (tgt[row] != MASK_ID_V) continue;
        float pmv = -3.0e38f, psv = 0.f;
        if (lane < npart) {
            pmv = pm[row * npart + lane];
            psv = ps[row * npart + lane];
        }
        float m = pmv;
#pragma unroll
        for (int off = 32; off; off >>= 1) m = fmaxf(m, __shfl_xor(m, off, 64));
        float sv = psv * __expf(pmv - m);
#pragma unroll
        for (int off = 32; off; off >>= 1) sv += __shfl_xor(sv, off, 64);
        if (lane == 0) {
            loss += numer[row] - (m + __logf(sv));
            cnt  += 1.f;
        }
    }

    __shared__ float sl[4], sc[4];
    if (lane == 0) { sl[wv] = loss; sc[wv] = cnt; }
    __syncthreads();
    if (tid == 0) {
        bl_loss[blockIdx.x] = sl[0] + sl[1] + sl[2] + sl[3];
        bl_cnt[blockIdx.x]  = sc[0] + sc[1] + sc[2] + sc[3];
    }
}

__global__ __launch_bounds__(256) void nce_finish_b(
    const float* __restrict__ bl_loss,
    const float* __restrict__ bl_cnt,
    float* __restrict__ out, int nblk)
{
    const int tid = threadIdx.x;
    float l = 0.f, c = 0.f;
    for (int i = tid; i < nblk; i += 256) { l += bl_loss[i]; c += bl_cnt[i]; }
    __shared__ float sl[256], sc[256];
    sl[tid] = l; sc[tid] = c;
    __syncthreads();
    for (int off = 128; off; off >>= 1) {
        if (tid < off) { sl[tid] += sl[tid + off]; sc[tid] += sc[tid + off]; }
        __syncthreads();
    }
    if (tid == 0) out[0] = -(sl[0] / sc[0]);
}

// ---------------------------------------------------------------------------
// Fallback (bf16 on-the-fly convert) — only if ws too small
// ---------------------------------------------------------------------------
__global__ __launch_bounds__(256, 2) void nce_gemm_fb(
    const float* __restrict__ x, const float* __restrict__ emb,
    float* __restrict__ numer, float* __restrict__ pm, float* __restrict__ ps)
{
    __shared__ ushort At[BM][LDW];
    __shared__ ushort Bt[BN][LDW];

    const int rb = blockIdx.x, cs = blockIdx.y;
    const int row0 = rb * BM, col0 = cs * SLICE_W;
    const int tid = threadIdx.x, lane = tid & 63, wid = tid >> 6;
    const int wr = wid >> 1, wc = wid & 1, l15 = lane & 15, lhi = lane >> 4;

    float m_run[16], s_run[16];
#pragma unroll
    for (int i = 0; i < 16; ++i) { m_run[i] = -3.0e38f; s_run[i] = 0.0f; }

    for (int ct = 0; ct < CTS; ++ct) {
        const int colt0 = col0 + ct * BN;
        f32x4 acc[4][4];
#pragma unroll
        for (int a = 0; a < 4; ++a)
#pragma unroll
            for (int b = 0; b < 4; ++b) acc[a][b] = f32x4{0.f,0.f,0.f,0.f};

#pragma unroll 1
        for (int kt = 0; kt < KST; ++kt) {
            __syncthreads();
#pragma unroll
            for (int i = 0; i < 4; ++i) {
                const int chunk = tid + i * 256;
                const int r = chunk >> 3, c8 = (chunk & 7) << 3;
                const float* ga = emb + (size_t)(row0 + r) * D_DIM + kt * BK + c8;
                float4 a0 = *(const float4*)(ga); float4 a1 = *(const float4*)(ga + 4);
                uint4 pa;
                pa.x = pk2bf(a0.x, a0.y); pa.y = pk2bf(a0.z, a0.w);
                pa.z = pk2bf(a1.x, a1.y); pa.w = pk2bf(a1.z, a1.w);
                *(uint4*)&At[r][c8] = pa;
                const float* gb = x + (size_t)(colt0 + r) * D_DIM + kt * BK + c8;
                float4 b0 = *(const float4*)(gb); float4 b1 = *(const float4*)(gb + 4);
                uint4 pb;
                pb.x = pk2bf(b0.x, b0.y); pb.y = pk2bf(b0.z, b0.w);
                pb.z = pk2bf(b1.x, b1.y); pb.w = pk2bf(b1.z, b1.w);
                *(uint4*)&Bt[r][c8] = pb;
            }
            __syncthreads();
#pragma unroll
            for (int kp = 0; kp < 2; ++kp) {
                const int ko = kp * 32 + lhi * 8;
                bf16x8 af[4], bfr[4];
#pragma unroll
                for (int mi = 0; mi < 4; ++mi)
                    af[mi] = *(const bf16x8*)&At[wr*64 + mi*16 + l15][ko];
#pragma unroll
                for (int ni = 0; ni < 4; ++ni)
                    bfr[ni] = *(const bf16x8*)&Bt[wc*64 + ni*16 + l15][ko];
#pragma unroll
                for (int mi = 0; mi < 4; ++mi)
#pragma unroll
                    for (int ni = 0; ni < 4; ++ni)
                        acc[mi][ni] = __builtin_amdgcn_mfma_f32_16x16x32_bf16(
                            af[mi], bfr[ni], acc[mi][ni], 0, 0, 0);
            }
        }

#pragma unroll
        for (int mi = 0; mi < 4; ++mi)
#pragma unroll
            for (int r = 0; r < 4; ++r) {
                const int row_g = row0 + wr*64 + mi*16 + lhi*4 + r;
#pragma unroll
                for (int ni = 0; ni < 4; ++ni) {
                    const int col_g = colt0 + wc*64 + ni*16 + l15;
                    if (row_g == col_g) numer[row_g] = acc[mi][ni][r];
                }
                const int idx = mi * 4 + r;
                const float v0 = acc[mi][0][r], v1 = acc[mi][1][r];
                const float v2 = acc[mi][2][r], v3 = acc[mi][3][r];
                const float mx = fmaxf(fmaxf(v0, v1), fmaxf(v2, v3));
                const float mn = fmaxf(m_run[idx], mx);
                const float scale = __expf(m_run[idx] - mn);
                s_run[idx] = s_run[idx] * scale
                           + __expf(v0 - mn) + __expf(v1 - mn)
                           + __expf(v2 - mn) + __expf(v3 - mn);
                m_run[idx] = mn;
            }
    }

#pragma unroll
    for (int idx = 0; idx < 16; ++idx) {
        float m = m_run[idx], s = s_run[idx];
#pragma unroll
        for (int off = 1; off < 16; off <<= 1) {
            const float mo = __shfl_xor(m, off, 64);
            const float so = __shfl_xor(s, off, 64);
            const float mn = fmaxf(m, mo);
            s = s * __expf(m - mn) + so * __expf(mo - mn);
            m = mn;
        }
        m_run[idx] = m; s_run[idx] = s;
    }

    if (l15 == 0) {
        const int slot = cs * 2 + wc;
#pragma unroll
        for (int mi = 0; mi < 4; ++mi)
#pragma unroll
            for (int r = 0; r < 4; ++r) {
                const int row_g = row0 + wr*64 + mi*16 + lhi*4 + r;
                pm[row_g * NPART_FB + slot] = m_run[mi*4 + r];
                ps[row_g * NPART_FB + slot] = s_run[mi*4 + r];
            }
    }
}

extern "C" void kernel_launch(void* const* d_in, const int* in_sizes, int n_in,
                              void* d_out, int out_size, void* d_ws, size_t ws_size,
                              hipStream_t stream) {
    (void)in_sizes; (void)n_in; (void)out_size;
    const float* x   = (const float*)d_in[0];
    const float* emb = (const float*)d_in[1];
    const int*   tgt = (const int*)d_in[2];
    float* out = (float*)d_out;

    const size_t elems = (size_t)N_TOK * D_DIM;
    const size_t need  = elems * 2
                       + (size_t)N_TOK * 4
                       + (size_t)N_TOK * NPART * 4 * 2
                       + FIN_BLOCKS * 8;

    if (ws_size >= need) {
        unsigned char* xb8 = (unsigned char*)d_ws;
        unsigned char* eb8 = xb8 + elems;
        float* numer = (float*)(eb8 + elems);
        float* pm    = numer + N_TOK;
        float* ps    = pm + (size_t)N_TOK * NPART;
        float* bl    = ps + (size_t)N_TOK * NPART;
        float* bc    = bl + FIN_BLOCKS;

        conv_fp8_frag<<<1024, 256, 0, stream>>>(x, emb, xb8, eb8);
        nce_gemm_fp8f<<<NSL2 * NSL2, 1024, 0, stream>>>(xb8, eb8, numer, pm, ps);
        nce_finish_a<<<FIN_BLOCKS, 256, 0, stream>>>(tgt, numer, pm, ps, bl, bc, NPART);
        nce_finish_b<<<1, 256, 0, stream>>>(bl, bc, out, FIN_BLOCKS);
    } else {
        float* numer = (float*)d_ws;
        float* pm    = numer + N_TOK;
        float* ps    = pm + (size_t)N_TOK * NPART_FB;
        float* bl    = ps + (size_t)N_TOK * NPART_FB;
        float* bc    = bl + FIN_BLOCKS;
        nce_gemm_fb<<<dim3(N_TOK / BM, NSLICE_FB), 256, 0, stream>>>(x, emb, numer, pm, ps);
        nce_finish_a<<<FIN_BLOCKS, 256, 0, stream>>>(tgt, numer, pm, ps, bl, bc, NPART_FB);
        nce_finish_b<<<1, 256, 0, stream>>>(bl, bc, out, FIN_BLOCKS);
    }
}